// Round 8
// baseline (554.273 us; speedup 1.0000x reference)
//
#include <hip/hip_runtime.h>

// Problem constants
#define TT 128
#define EE 192
#define HH 192
#define SCALE_F 0.07216878364870322f
#define LOG2E_F 1.4426950408889634f

typedef float f32x4 __attribute__((ext_vector_type(4)));
typedef short short8 __attribute__((ext_vector_type(8)));
typedef short short4v __attribute__((ext_vector_type(4)));

__device__ inline unsigned short f2bf(float x) {
  union { float f; unsigned u; } v; v.f = x;
  unsigned r = v.u + 0x7FFFu + ((v.u >> 16) & 1u);
  return (unsigned short)(r >> 16);
}
__device__ inline unsigned pack2bf(float a, float b) {
  return (unsigned)f2bf(a) | ((unsigned)f2bf(b) << 16);
}

// ---------------------------------------------------------------------------
// pack_w: W[h][e] fp32 -> frag-major bf16.
// frag f = widx*72 + tile*6 + es; lane(lg,lr) j=0..7 -> W[16*tile+lr][32*es+8*lg+j]
// ---------------------------------------------------------------------------
__global__ void pack_w(const float* __restrict__ Wq, const float* __restrict__ Wk,
                       const float* __restrict__ Wv, short* __restrict__ out) {
  int f = blockIdx.x * 4 + (threadIdx.x >> 6);
  int lane = threadIdx.x & 63, lg = lane >> 4, lr = lane & 15;
  int widx = f / 72, rem = f % 72, tile = rem / 6, es = rem % 6;
  const float* W = (widx == 0) ? Wq : ((widx == 1) ? Wk : Wv);
  const float* p = W + (16 * tile + lr) * EE + 32 * es + 8 * lg;
  float4 a = *(const float4*)p;
  float4 b = *(const float4*)(p + 4);
  short8 h;
  h[0] = (short)f2bf(a.x); h[1] = (short)f2bf(a.y);
  h[2] = (short)f2bf(a.z); h[3] = (short)f2bf(a.w);
  h[4] = (short)f2bf(b.x); h[5] = (short)f2bf(b.y);
  h[6] = (short)f2bf(b.z); h[7] = (short)f2bf(b.w);
  *(short8*)(out + ((size_t)f * 64 + lane) * 8) = h;
}

// ---------------------------------------------------------------------------
// K1: QKV projection -> frag-major global. Block = (batch, m-quad): 4 waves,
// wave w owns m-tile mt = q4*4+w. ZERO barriers (K transpose is wave-private
// LDS; V transpose folds into contiguous 8B stores).
// Outputs:
//   qws: QK B-frags  (b*48 + qt*6 + ha)*1KB : lane 16B = Q[16qt+lr][32ha+8lg+j]
//   kvws (=d_out): K A-frags  b*98304 + (kt*6+ha)*1KB : lane = K[16kt+lr][32ha+8lg+j]
//                  V^T A-frags b*98304+49152 + (tp*12+ht)*1KB :
//                                  lane 16B = V[32tp+8lg+j][16ht+lr]
// ---------------------------------------------------------------------------
__global__ __launch_bounds__(256)
void qkv_frag(const float* __restrict__ x, const short* __restrict__ wf,
              char* __restrict__ qws, char* __restrict__ kvws) {
  __shared__ char lds[24576];  // 6KB per wave (private K transpose)
  const int b = blockIdx.x >> 1, q4 = blockIdx.x & 1;
  const int tid = threadIdx.x;
  const int w = tid >> 6, lane = tid & 63, lg = lane >> 4, lr = lane & 15;
  const int mt = q4 * 4 + w;
  const short* wfq = wf;
  const short* wfk = wf + 36864;
  const short* wfv = wf + 73728;
  const f32x4 zero = {0.f, 0.f, 0.f, 0.f};
  const float* xb = x + (size_t)b * (TT * EE);

  // x A/B-fragments for rows 16*mt+lr
  short8 xq[6];
#pragma unroll
  for (int es = 0; es < 6; ++es) {
    const float* p = xb + (16 * mt + lr) * EE + 32 * es + 8 * lg;
    float4 u = *(const float4*)p, v = *(const float4*)(p + 4);
    short8 h;
    h[0] = (short)f2bf(u.x); h[1] = (short)f2bf(u.y);
    h[2] = (short)f2bf(u.z); h[3] = (short)f2bf(u.w);
    h[4] = (short)f2bf(v.x); h[5] = (short)f2bf(v.y);
    h[6] = (short)f2bf(v.z); h[7] = (short)f2bf(v.w);
    xq[es] = h;
  }

  // ---- Q: Q^T = mfma(Wq-frag, xq) -> pack -> shuffle to B-frag -> store ----
  {
    unsigned wqp[12][2];
#pragma unroll
    for (int ht = 0; ht < 12; ++ht) {
      f32x4 a = zero;
#pragma unroll
      for (int es = 0; es < 6; ++es) {
        short8 wg = *(const short8*)(wfq + ((size_t)(ht * 6 + es) * 64 + lane) * 8);
        a = __builtin_amdgcn_mfma_f32_16x16x32_bf16(wg, xq[es], a, 0, 0, 0);
      }
      wqp[ht][0] = pack2bf(a[0], a[1]);
      wqp[ht][1] = pack2bf(a[2], a[3]);
    }
#pragma unroll
    for (int ha = 0; ha < 6; ++ha) {
      union { unsigned d[4]; short8 v; } au;
#pragma unroll
      for (int i = 0; i < 4; ++i) {
        int sl = ((2 * (lg & 1) + (i >> 1)) << 4) | lr;
        unsigned v0 = (unsigned)__shfl((int)wqp[2 * ha][i & 1], sl);
        unsigned v1 = (unsigned)__shfl((int)wqp[2 * ha + 1][i & 1], sl);
        au.d[i] = (lg >> 1) ? v1 : v0;
      }
      *(short8*)(qws + ((size_t)(b * 48 + mt * 6 + ha) * 64 + lane) * 16) = au.v;
    }
  }

  // ---- K: mfma -> wave-private LDS transpose -> coalesced frag store ----
  char* kreg = lds + w * 6144;
#pragma unroll
  for (int nt = 0; nt < 12; ++nt) {
    f32x4 a0 = zero;
#pragma unroll
    for (int es = 0; es < 6; ++es) {
      short8 wg = *(const short8*)(wfk + ((size_t)(nt * 6 + es) * 64 + lane) * 8);
      a0 = __builtin_amdgcn_mfma_f32_16x16x32_bf16(xq[es], wg, a0, 0, 0, 0);
    }
    // K[16mt+4lg+r][16nt+lr] -> frag ha=nt>>1, lane(lg2,4lg+r), byte j=lr&7
    int lg2 = 2 * (nt & 1) + (lr >> 3), j = lr & 7;
#pragma unroll
    for (int r = 0; r < 4; ++r)
      *(unsigned short*)(kreg + (nt >> 1) * 1024 +
                         ((lg2 * 16 + 4 * lg + r) << 4) + j * 2) = f2bf(a0[r]);
  }
  {
    char* kgb = kvws + (size_t)b * 98304 + (size_t)mt * 6144;
#pragma unroll
    for (int ha = 0; ha < 6; ++ha) {
      short8 kf = *(const short8*)(kreg + ha * 1024 + lane * 16);
      *(short8*)(kgb + ha * 1024 + lane * 16) = kf;
    }
  }

  // ---- V: mfma -> direct V^T A-frag stores (4 bf16 along t = 8B contig) ----
  {
    char* vgb = kvws + (size_t)b * 98304 + 49152;
    const int tpg = q4 * 2 + (w >> 1);       // global tp of this wave's rows
    const int lgp = 2 * (w & 1) + (lg >> 1); // lane-group in target frag
#pragma unroll
    for (int nt = 0; nt < 12; ++nt) {
      f32x4 a0 = zero;
#pragma unroll
      for (int es = 0; es < 6; ++es) {
        short8 wg = *(const short8*)(wfv + ((size_t)(nt * 6 + es) * 64 + lane) * 8);
        a0 = __builtin_amdgcn_mfma_f32_16x16x32_bf16(xq[es], wg, a0, 0, 0, 0);
      }
      // V[16mt+4lg+r][16nt+lr] -> frag(tp=mt>>1, ht=nt), lane(lgp,lr),
      // bytes j=(4lg+r)&7 -> r=0..3 contiguous 8B at offset (lg&1)*8
      short4v p4;
      p4[0] = (short)f2bf(a0[0]); p4[1] = (short)f2bf(a0[1]);
      p4[2] = (short)f2bf(a0[2]); p4[3] = (short)f2bf(a0[3]);
      *(short4v*)(vgb + (size_t)(tpg * 12 + nt) * 1024 +
                  ((lgp * 16 + lr) << 4) + (lg & 1) * 8) = p4;
    }
  }
}

// ---------------------------------------------------------------------------
// K2: attention, LDS-free, loads all operands as ready MFMA fragments.
// Block = 1 batch (8 waves, wave = q-tile). One barrier only: all K/V reads
// complete before O overwrites d_out[b]. Output via O^T = mfma(V^T-frag, pa)
// -> float4 stores.
// ---------------------------------------------------------------------------
__global__ __launch_bounds__(512)
void attn_frag(const char* __restrict__ qws, char* __restrict__ kv) {
  const int b = blockIdx.x;
  const int tid = threadIdx.x;
  const int qt = tid >> 6, lane = tid & 63, lg = lane >> 4, lr = lane & 15;
  const char* kb = kv + (size_t)b * 98304;
  const char* vb = kb + 49152;
  const f32x4 zero = {0.f, 0.f, 0.f, 0.f};

  // Q B-frags (precomputed layout): lane j -> Q[16qt+lr][32ha+8lg+j]
  short8 qb[6];
#pragma unroll
  for (int ha = 0; ha < 6; ++ha)
    qb[ha] = *(const short8*)(qws + ((size_t)(b * 48 + qt * 6 + ha) * 64 + lane) * 16);

  // QK^T: S^T = mfma(K-frag, qb): lane holds S^T[16kt+4lg+r][16qt+lr]
  f32x4 sa[8];
#pragma unroll
  for (int kt = 0; kt < 8; ++kt) sa[kt] = zero;
#pragma unroll
  for (int kt = 0; kt < 8; ++kt) {
    if (kt <= qt) {
#pragma unroll
      for (int ha = 0; ha < 6; ++ha) {
        short8 ka = *(const short8*)(kb + (size_t)(kt * 6 + ha) * 1024 + lane * 16);
        sa[kt] = __builtin_amdgcn_mfma_f32_16x16x32_bf16(ka, qb[ha], sa[kt], 0, 0, 0);
      }
    }
  }

  // softmax over row q=16qt+lr (in-lane + 2 shfl_xor across lg)
  const float CSC = SCALE_F * LOG2E_F;
  float m = -INFINITY;
#pragma unroll
  for (int kt = 0; kt < 8; ++kt)
    if (kt <= qt) {
#pragma unroll
      for (int r = 0; r < 4; ++r) {
        float v = sa[kt][r] * CSC;
        if (kt == qt && 4 * lg + r > lr) v = -INFINITY;  // causal diagonal
        sa[kt][r] = v;
        m = fmaxf(m, v);
      }
    }
  m = fmaxf(m, __shfl_xor(m, 16));
  m = fmaxf(m, __shfl_xor(m, 32));
  float sum = 0.f;
#pragma unroll
  for (int kt = 0; kt < 8; ++kt)
    if (kt <= qt) {
#pragma unroll
      for (int r = 0; r < 4; ++r) {
        float p = exp2f(sa[kt][r] - m);
        sa[kt][r] = p;
        sum += p;
      }
    }
  sum += __shfl_xor(sum, 16);
  sum += __shfl_xor(sum, 32);
  const float rinv = 1.0f / sum;

  unsigned pw[8][2];
#pragma unroll
  for (int kt = 0; kt < 8; ++kt) { pw[kt][0] = 0u; pw[kt][1] = 0u; }
#pragma unroll
  for (int kt = 0; kt < 8; ++kt)
    if (kt <= qt) {
      pw[kt][0] = pack2bf(sa[kt][0] * rinv, sa[kt][1] * rinv);
      pw[kt][1] = pack2bf(sa[kt][2] * rinv, sa[kt][3] * rinv);
    }

  // pa[tp]: lane j -> P[q=16qt+lr][t=32tp+8lg+j]  (B-operand for O^T mfma)
  short8 pa[4];
#pragma unroll
  for (int tp = 0; tp < 4; ++tp) {
    union { unsigned d[4]; short8 v; } au;
#pragma unroll
    for (int i = 0; i < 4; ++i) {
      int sl = ((2 * (lg & 1) + (i >> 1)) << 4) | lr;
      unsigned lo = (unsigned)__shfl((int)pw[2 * tp][i & 1], sl);
      unsigned hi = (unsigned)__shfl((int)pw[2 * tp + 1][i & 1], sl);
      au.d[i] = (lg >> 1) ? hi : lo;
    }
    pa[tp] = au.v;
  }

  // O^T = mfma(V^T-frag, pa): lane holds O^T[16ht+4lg+r][16qt+lr]
  f32x4 ot[12];
#pragma unroll
  for (int ht = 0; ht < 12; ++ht) ot[ht] = zero;
#pragma unroll
  for (int tp = 0; tp < 4; ++tp) {
    if (tp <= (qt >> 1)) {
#pragma unroll
      for (int ht = 0; ht < 12; ++ht) {
        short8 va = *(const short8*)(vb + (size_t)(tp * 12 + ht) * 1024 + lane * 16);
        ot[ht] = __builtin_amdgcn_mfma_f32_16x16x32_bf16(va, pa[tp], ot[ht], 0, 0, 0);
      }
    }
  }

  __syncthreads();  // all waves' K/V reads drained before overwriting d_out[b]

  // O[q][h]: 4 consecutive h per lane -> float4 stores
  float* ob = (float*)(kv + (size_t)b * 98304);
#pragma unroll
  for (int ht = 0; ht < 12; ++ht)
    *(f32x4*)(ob + (16 * qt + lr) * HH + 16 * ht + 4 * lg) = ot[ht];
}

extern "C" void kernel_launch(void* const* d_in, const int* in_sizes, int n_in,
                              void* d_out, int out_size, void* d_ws, size_t ws_size,
                              hipStream_t stream) {
  const float* x  = (const float*)d_in[0];
  const float* Wq = (const float*)d_in[1];
  const float* Wk = (const float*)d_in[2];
  const float* Wv = (const float*)d_in[3];
  int Bn = in_sizes[0] / (TT * EE);

  char*  qws = (char*)d_ws;                                   // Bn*49152 B
  short* wsW = (short*)((char*)d_ws + (size_t)Bn * 49152);    // 221184 B

  hipLaunchKernelGGL(pack_w, dim3(54), dim3(256), 0, stream, Wq, Wk, Wv, wsW);
  hipLaunchKernelGGL(qkv_frag, dim3(2 * Bn), dim3(256), 0, stream,
                     x, wsW, qws, (char*)d_out);
  hipLaunchKernelGGL(attn_frag, dim3(Bn), dim3(512), 0, stream,
                     qws, (char*)d_out);
}

// Round 9
// 313.809 us; speedup vs baseline: 1.7663x; 1.7663x over previous
//
#include <hip/hip_runtime.h>

// Problem constants
#define TT 128
#define EE 192
#define HH 192
#define SCALE_F 0.07216878364870322f
#define LOG2E_F 1.4426950408889634f

typedef float f32x4 __attribute__((ext_vector_type(4)));
typedef short short8 __attribute__((ext_vector_type(8)));
typedef short short4v __attribute__((ext_vector_type(4)));

__device__ inline unsigned short f2bf(float x) {
  union { float f; unsigned u; } v; v.f = x;
  unsigned r = v.u + 0x7FFFu + ((v.u >> 16) & 1u);
  return (unsigned short)(r >> 16);
}
__device__ inline unsigned pack2bf(float a, float b) {
  return (unsigned)f2bf(a) | ((unsigned)f2bf(b) << 16);
}

// ---------------------------------------------------------------------------
// pack_w: W[h][e] fp32 -> frag-major bf16 in ws.
// frag f = widx*72 + tile*6 + es; lane(lg,lr) j=0..7 -> W[16*tile+lr][32*es+8*lg+j]
// ---------------------------------------------------------------------------
__global__ void pack_w(const float* __restrict__ Wq, const float* __restrict__ Wk,
                       const float* __restrict__ Wv, short* __restrict__ out) {
  int f = blockIdx.x * 4 + (threadIdx.x >> 6);
  int lane = threadIdx.x & 63, lg = lane >> 4, lr = lane & 15;
  int widx = f / 72, rem = f % 72, tile = rem / 6, es = rem % 6;
  const float* W = (widx == 0) ? Wq : ((widx == 1) ? Wk : Wv);
  const float* p = W + (16 * tile + lr) * EE + 32 * es + 8 * lg;
  float4 a = *(const float4*)p;
  float4 b = *(const float4*)(p + 4);
  short8 h;
  h[0] = (short)f2bf(a.x); h[1] = (short)f2bf(a.y);
  h[2] = (short)f2bf(a.z); h[3] = (short)f2bf(a.w);
  h[4] = (short)f2bf(b.x); h[5] = (short)f2bf(b.y);
  h[6] = (short)f2bf(b.z); h[7] = (short)f2bf(b.w);
  *(short8*)(out + ((size_t)f * 64 + lane) * 8) = h;
}

// ---------------------------------------------------------------------------
// proj_pair: transpose-GEMM + shuffle for Q or K tile-pair p (tiles 2p, 2p+1).
// Weights (12 frags, 12KB contiguous) register-resident; loops 8 m-tiles
// reading x-frags from LDS. Produces frag lane j -> M[16mt+lr][32p+8lg+j]
// (B-frag layout for Q, identical storage to A-frag layout for K).
// dstbase already includes p*1024 + lane*16; per-mt stride 6144.
// ---------------------------------------------------------------------------
__device__ __forceinline__ void proj_pair(const char* smem, const short* wsrc,
                                          int p, char* dstbase,
                                          int lg, int lr, int lane) {
  const f32x4 zero = {0.f, 0.f, 0.f, 0.f};
  short8 wg[12];
#pragma unroll
  for (int i = 0; i < 12; ++i)
    wg[i] = *(const short8*)((const char*)wsrc + ((size_t)(p * 12 + i) * 64 + lane) * 16);
#pragma unroll
  for (int mt = 0; mt < 8; ++mt) {
    f32x4 a0 = zero, a1 = zero;
#pragma unroll
    for (int es = 0; es < 6; ++es) {
      short8 xf = *(const short8*)(smem + (mt * 6 + es) * 1024 + lane * 16);
      a0 = __builtin_amdgcn_mfma_f32_16x16x32_bf16(wg[es], xf, a0, 0, 0, 0);
      a1 = __builtin_amdgcn_mfma_f32_16x16x32_bf16(wg[6 + es], xf, a1, 0, 0, 0);
    }
    // D = (proj)^T[16tile+4lg+r][16mt+lr]; pack + shuffle to row-major frag
    unsigned w00 = pack2bf(a0[0], a0[1]), w01 = pack2bf(a0[2], a0[3]);
    unsigned w10 = pack2bf(a1[0], a1[1]), w11 = pack2bf(a1[2], a1[3]);
    union { unsigned d[4]; short8 v; } au;
#pragma unroll
    for (int i = 0; i < 4; ++i) {
      int sl = ((2 * (lg & 1) + (i >> 1)) << 4) | lr;
      unsigned v0 = (unsigned)__shfl((int)(i & 1 ? w01 : w00), sl);
      unsigned v1 = (unsigned)__shfl((int)(i & 1 ? w11 : w10), sl);
      au.d[i] = (lg >> 1) ? v1 : v0;
    }
    *(short8*)(dstbase + mt * 6144) = au.v;
  }
}

// ---------------------------------------------------------------------------
// proj_v: row-major GEMM for V n-tile nt; direct V^T A-frag stores (8B contig).
// ---------------------------------------------------------------------------
__device__ __forceinline__ void proj_v(const char* smem, const short* wfv,
                                       int nt, char* vgb,
                                       int lg, int lr, int lane) {
  const f32x4 zero = {0.f, 0.f, 0.f, 0.f};
  short8 wg[6];
#pragma unroll
  for (int i = 0; i < 6; ++i)
    wg[i] = *(const short8*)((const char*)wfv + ((size_t)(nt * 6 + i) * 64 + lane) * 16);
#pragma unroll
  for (int mt = 0; mt < 8; ++mt) {
    f32x4 a0 = zero;
#pragma unroll
    for (int es = 0; es < 6; ++es) {
      short8 xf = *(const short8*)(smem + (mt * 6 + es) * 1024 + lane * 16);
      a0 = __builtin_amdgcn_mfma_f32_16x16x32_bf16(xf, wg[es], a0, 0, 0, 0);
    }
    // V[16mt+4lg+r][16nt+lr] -> frag(tp=mt>>1, ht=nt), lane(2*(mt&1)+(lg>>1), lr),
    // r=0..3 contiguous 8B at sub-offset (lg&1)*8
    short4v p4;
    p4[0] = (short)f2bf(a0[0]); p4[1] = (short)f2bf(a0[1]);
    p4[2] = (short)f2bf(a0[2]); p4[3] = (short)f2bf(a0[3]);
    *(short4v*)(vgb + (size_t)((mt >> 1) * 12 + nt) * 1024 +
                ((2 * (mt & 1) + (lg >> 1)) * 16 + lr) * 16 + (lg & 1) * 8) = p4;
  }
}

// ---------------------------------------------------------------------------
// K1: QKV projection GEMM. Block = 1 batch, 8 waves, 48KB LDS, ONE barrier.
// x staged once to LDS as MFMA frags; weights register-resident per unit;
// each weight frag reused across all 8 m-tiles. 24 units (6 Qpair, 6 Kpair,
// 12 V) distributed over 8 waves via packed tables (4/4/4/4/5/5/5/5 wgt).
// ---------------------------------------------------------------------------
__global__ __launch_bounds__(512)
void qkv_gemm(const float* __restrict__ x, const short* __restrict__ wf,
              char* __restrict__ qws, char* __restrict__ kvws) {
  __shared__ char smem[49152];
  const int b = blockIdx.x;
  const int tid = threadIdx.x;
  const int w = tid >> 6, lane = tid & 63, lg = lane >> 4, lr = lane & 15;
  const float* xb = x + (size_t)b * (TT * EE);

  // ---- stage x -> LDS frags: frag(mt,es) lane j = X[16mt+lr][32es+8lg+j] ----
#pragma unroll
  for (int i = 0; i < 6; ++i) {
    int idx = tid + 512 * i;          // 3072 (row, col-block) pairs
    int t = idx & 127, cb = idx >> 7; // row 0..127, 8-col block 0..23
    const float* p = xb + t * EE + cb * 8;
    float4 u = *(const float4*)p, v = *(const float4*)(p + 4);
    short8 h;
    h[0] = (short)f2bf(u.x); h[1] = (short)f2bf(u.y);
    h[2] = (short)f2bf(u.z); h[3] = (short)f2bf(u.w);
    h[4] = (short)f2bf(v.x); h[5] = (short)f2bf(v.y);
    h[6] = (short)f2bf(v.z); h[7] = (short)f2bf(v.w);
    *(short8*)(smem + ((t >> 4) * 6 + (cb >> 2)) * 1024 +
               ((cb & 3) * 16 + (t & 15)) * 16) = h;
  }
  __syncthreads();

  const short* wfq = wf;
  const short* wfk = wf + 36864;
  const short* wfv = wf + 73728;
  char* qbase = qws + (size_t)b * 49152 + lane * 16;
  char* kvb = kvws + (size_t)b * 98304;
  char* kbase = kvb + lane * 16;
  char* vgb = kvb + 49152;

  // unit tables: byte = (type<<4)|param; type 0=Qpair 1=Kpair 2=V
  const unsigned long long T0 = 0x1303120211011000ULL;  // ui 0..7
  const unsigned long long T1 = 0x2322211514200504ULL;  // ui 8..15
  const unsigned long long T2 = 0x2B2A292827262524ULL;  // ui 16..23
  const int u0 = (int)((0x130E0B0806040200ULL >> (w * 8)) & 0xFF);
  const int u1 = (int)((0x18130E0B08060402ULL >> (w * 8)) & 0xFF);

  for (int ui = u0; ui < u1; ++ui) {
    unsigned code = (unsigned)((ui < 8 ? T0 : (ui < 16 ? T1 : T2)) >> ((ui & 7) * 8)) & 0xFFu;
    int ty = code >> 4, p = code & 15;
    if (ty == 0)      proj_pair(smem, wfq, p, qbase + p * 1024, lg, lr, lane);
    else if (ty == 1) proj_pair(smem, wfk, p, kbase + p * 1024, lg, lr, lane);
    else              proj_v(smem, wfv, p, vgb, lg, lr, lane);
  }
}

// ---------------------------------------------------------------------------
// K2: attention, LDS-free, loads all operands as ready MFMA fragments.
// Block = 1 batch (8 waves, wave = q-tile). One barrier only: all K/V reads
// complete before O overwrites d_out[b]. O^T = mfma(V^T-frag, pa) -> f32x4.
// ---------------------------------------------------------------------------
__global__ __launch_bounds__(512)
void attn_frag(const char* __restrict__ qws, char* __restrict__ kv) {
  const int b = blockIdx.x;
  const int tid = threadIdx.x;
  const int qt = tid >> 6, lane = tid & 63, lg = lane >> 4, lr = lane & 15;
  const char* kb = kv + (size_t)b * 98304;
  const char* vb = kb + 49152;
  const f32x4 zero = {0.f, 0.f, 0.f, 0.f};

  // pa[tp]: lane j -> P[q=16qt+lr][t=32tp+8lg+j] (built below)
  short8 pa[4];
  {
    // Q B-frags: lane j -> Q[16qt+lr][32ha+8lg+j]
    short8 qb[6];
#pragma unroll
    for (int ha = 0; ha < 6; ++ha)
      qb[ha] = *(const short8*)(qws + ((size_t)(b * 48 + qt * 6 + ha) * 64 + lane) * 16);

    // QK^T: S^T = mfma(K-frag, qb): lane holds S^T[16kt+4lg+r][16qt+lr]
    f32x4 sa[8];
#pragma unroll
    for (int kt = 0; kt < 8; ++kt) sa[kt] = zero;
#pragma unroll
    for (int kt = 0; kt < 8; ++kt) {
      if (kt <= qt) {
#pragma unroll
        for (int ha = 0; ha < 6; ++ha) {
          short8 ka = *(const short8*)(kb + (size_t)(kt * 6 + ha) * 1024 + lane * 16);
          sa[kt] = __builtin_amdgcn_mfma_f32_16x16x32_bf16(ka, qb[ha], sa[kt], 0, 0, 0);
        }
      }
    }

    // softmax over row q=16qt+lr (in-lane + 2 shfl_xor across lg)
    const float CSC = SCALE_F * LOG2E_F;
    float m = -INFINITY;
#pragma unroll
    for (int kt = 0; kt < 8; ++kt)
      if (kt <= qt) {
#pragma unroll
        for (int r = 0; r < 4; ++r) {
          float v = sa[kt][r] * CSC;
          if (kt == qt && 4 * lg + r > lr) v = -INFINITY;  // causal diagonal
          sa[kt][r] = v;
          m = fmaxf(m, v);
        }
      }
    m = fmaxf(m, __shfl_xor(m, 16));
    m = fmaxf(m, __shfl_xor(m, 32));
    float sum = 0.f;
#pragma unroll
    for (int kt = 0; kt < 8; ++kt)
      if (kt <= qt) {
#pragma unroll
        for (int r = 0; r < 4; ++r) {
          float p = exp2f(sa[kt][r] - m);
          sa[kt][r] = p;
          sum += p;
        }
      }
    sum += __shfl_xor(sum, 16);
    sum += __shfl_xor(sum, 32);
    const float rinv = 1.0f / sum;

    unsigned pw[8][2];
#pragma unroll
    for (int kt = 0; kt < 8; ++kt) { pw[kt][0] = 0u; pw[kt][1] = 0u; }
#pragma unroll
    for (int kt = 0; kt < 8; ++kt)
      if (kt <= qt) {
        pw[kt][0] = pack2bf(sa[kt][0] * rinv, sa[kt][1] * rinv);
        pw[kt][1] = pack2bf(sa[kt][2] * rinv, sa[kt][3] * rinv);
      }

#pragma unroll
    for (int tp = 0; tp < 4; ++tp) {
      union { unsigned d[4]; short8 v; } au;
#pragma unroll
      for (int i = 0; i < 4; ++i) {
        int sl = ((2 * (lg & 1) + (i >> 1)) << 4) | lr;
        unsigned lo = (unsigned)__shfl((int)pw[2 * tp][i & 1], sl);
        unsigned hi = (unsigned)__shfl((int)pw[2 * tp + 1][i & 1], sl);
        au.d[i] = (lg >> 1) ? hi : lo;
      }
      pa[tp] = au.v;
    }
  }

  // O^T = mfma(V^T-frag, pa): lane holds O^T[16ht+4lg+r][16qt+lr]
  f32x4 ot[12];
#pragma unroll
  for (int ht = 0; ht < 12; ++ht) ot[ht] = zero;
#pragma unroll
  for (int tp = 0; tp < 4; ++tp) {
    if (tp <= (qt >> 1)) {
#pragma unroll
      for (int ht = 0; ht < 12; ++ht) {
        short8 va = *(const short8*)(vb + (size_t)(tp * 12 + ht) * 1024 + lane * 16);
        ot[ht] = __builtin_amdgcn_mfma_f32_16x16x32_bf16(va, pa[tp], ot[ht], 0, 0, 0);
      }
    }
  }

  __syncthreads();  // all waves' K/V reads drained before overwriting d_out[b]

  // O[q][h]: 4 consecutive h per lane -> f32x4 stores
  float* ob = (float*)(kv + (size_t)b * 98304);
#pragma unroll
  for (int ht = 0; ht < 12; ++ht)
    *(f32x4*)(ob + (16 * qt + lr) * HH + 16 * ht + 4 * lg) = ot[ht];
}

extern "C" void kernel_launch(void* const* d_in, const int* in_sizes, int n_in,
                              void* d_out, int out_size, void* d_ws, size_t ws_size,
                              hipStream_t stream) {
  const float* x  = (const float*)d_in[0];
  const float* Wq = (const float*)d_in[1];
  const float* Wk = (const float*)d_in[2];
  const float* Wv = (const float*)d_in[3];
  int Bn = in_sizes[0] / (TT * EE);

  char*  qws = (char*)d_ws;                                 // Bn*49152 B
  short* wsW = (short*)((char*)d_ws + (size_t)Bn * 49152);  // 221184 B

  hipLaunchKernelGGL(pack_w, dim3(54), dim3(256), 0, stream, Wq, Wk, Wv, wsW);
  hipLaunchKernelGGL(qkv_gemm, dim3(Bn), dim3(512), 0, stream,
                     x, wsW, qws, (char*)d_out);
  hipLaunchKernelGGL(attn_frag, dim3(Bn), dim3(512), 0, stream,
                     qws, (char*)d_out);
}

// Round 10
// 250.378 us; speedup vs baseline: 2.2138x; 1.2533x over previous
//
#include <hip/hip_runtime.h>

// Problem constants
#define TT 128
#define EE 192
#define HH 192
#define SCALE_F 0.07216878364870322f
#define LOG2E_F 1.4426950408889634f

typedef float f32x4 __attribute__((ext_vector_type(4)));
typedef short short8 __attribute__((ext_vector_type(8)));
typedef short short4v __attribute__((ext_vector_type(4)));

__device__ inline unsigned short f2bf(float x) {
  union { float f; unsigned u; } v; v.f = x;
  unsigned r = v.u + 0x7FFFu + ((v.u >> 16) & 1u);
  return (unsigned short)(r >> 16);
}
__device__ inline unsigned pack2bf(float a, float b) {
  return (unsigned)f2bf(a) | ((unsigned)f2bf(b) << 16);
}

// ---------------------------------------------------------------------------
// pack_w: W[h][e] fp32 -> frag-major bf16 in ws.
// frag f = widx*72 + tile*6 + es; lane(lg,lr) j=0..7 -> W[16*tile+lr][32*es+8*lg+j]
// ---------------------------------------------------------------------------
__global__ void pack_w(const float* __restrict__ Wq, const float* __restrict__ Wk,
                       const float* __restrict__ Wv, short* __restrict__ out) {
  int f = blockIdx.x * 4 + (threadIdx.x >> 6);
  int lane = threadIdx.x & 63, lg = lane >> 4, lr = lane & 15;
  int widx = f / 72, rem = f % 72, tile = rem / 6, es = rem % 6;
  const float* W = (widx == 0) ? Wq : ((widx == 1) ? Wk : Wv);
  const float* p = W + (16 * tile + lr) * EE + 32 * es + 8 * lg;
  float4 a = *(const float4*)p;
  float4 b = *(const float4*)(p + 4);
  short8 h;
  h[0] = (short)f2bf(a.x); h[1] = (short)f2bf(a.y);
  h[2] = (short)f2bf(a.z); h[3] = (short)f2bf(a.w);
  h[4] = (short)f2bf(b.x); h[5] = (short)f2bf(b.y);
  h[6] = (short)f2bf(b.z); h[7] = (short)f2bf(b.w);
  *(short8*)(out + ((size_t)f * 64 + lane) * 8) = h;
}

// ---------------------------------------------------------------------------
// proj_pair: transpose-GEMM + shuffle for Q or K tile-pair p (tiles 2p, 2p+1).
// Weights (12 frags) register-resident; loops 8 m-tiles reading x from LDS.
// Produces frag lane j -> M[16mt+lr][32p+8lg+j].
// ---------------------------------------------------------------------------
__device__ __forceinline__ void proj_pair(const char* smem, const short* wsrc,
                                          int p, char* dstbase,
                                          int lg, int lr, int lane) {
  const f32x4 zero = {0.f, 0.f, 0.f, 0.f};
  short8 wg[12];
#pragma unroll
  for (int i = 0; i < 12; ++i)
    wg[i] = *(const short8*)((const char*)wsrc + ((size_t)(p * 12 + i) * 64 + lane) * 16);
#pragma unroll
  for (int mt = 0; mt < 8; ++mt) {
    f32x4 a0 = zero, a1 = zero;
#pragma unroll
    for (int es = 0; es < 6; ++es) {
      short8 xf = *(const short8*)(smem + (mt * 6 + es) * 1024 + lane * 16);
      a0 = __builtin_amdgcn_mfma_f32_16x16x32_bf16(wg[es], xf, a0, 0, 0, 0);
      a1 = __builtin_amdgcn_mfma_f32_16x16x32_bf16(wg[6 + es], xf, a1, 0, 0, 0);
    }
    unsigned w00 = pack2bf(a0[0], a0[1]), w01 = pack2bf(a0[2], a0[3]);
    unsigned w10 = pack2bf(a1[0], a1[1]), w11 = pack2bf(a1[2], a1[3]);
    union { unsigned d[4]; short8 v; } au;
#pragma unroll
    for (int i = 0; i < 4; ++i) {
      int sl = ((2 * (lg & 1) + (i >> 1)) << 4) | lr;
      unsigned v0 = (unsigned)__shfl((int)(i & 1 ? w01 : w00), sl);
      unsigned v1 = (unsigned)__shfl((int)(i & 1 ? w11 : w10), sl);
      au.d[i] = (lg >> 1) ? v1 : v0;
    }
    *(short8*)(dstbase + mt * 6144) = au.v;
  }
}

// ---------------------------------------------------------------------------
// proj_v: row-major GEMM for V n-tile nt; direct V^T A-frag stores (8B contig).
// ---------------------------------------------------------------------------
__device__ __forceinline__ void proj_v(const char* smem, const short* wfv,
                                       int nt, char* vgb,
                                       int lg, int lr, int lane) {
  const f32x4 zero = {0.f, 0.f, 0.f, 0.f};
  short8 wg[6];
#pragma unroll
  for (int i = 0; i < 6; ++i)
    wg[i] = *(const short8*)((const char*)wfv + ((size_t)(nt * 6 + i) * 64 + lane) * 16);
#pragma unroll
  for (int mt = 0; mt < 8; ++mt) {
    f32x4 a0 = zero;
#pragma unroll
    for (int es = 0; es < 6; ++es) {
      short8 xf = *(const short8*)(smem + (mt * 6 + es) * 1024 + lane * 16);
      a0 = __builtin_amdgcn_mfma_f32_16x16x32_bf16(xf, wg[es], a0, 0, 0, 0);
    }
    short4v p4;
    p4[0] = (short)f2bf(a0[0]); p4[1] = (short)f2bf(a0[1]);
    p4[2] = (short)f2bf(a0[2]); p4[3] = (short)f2bf(a0[3]);
    *(short4v*)(vgb + (size_t)((mt >> 1) * 12 + nt) * 1024 +
                ((2 * (mt & 1) + (lg >> 1)) * 16 + lr) * 16 + (lg & 1) * 8) = p4;
  }
}

// ---------------------------------------------------------------------------
// K1: QKV projection GEMM. Block = 1 batch, 8 waves, 48KB LDS, ONE barrier.
// ---------------------------------------------------------------------------
__global__ __launch_bounds__(512)
void qkv_gemm(const float* __restrict__ x, const short* __restrict__ wf,
              char* __restrict__ qws, char* __restrict__ kvws) {
  __shared__ char smem[49152];
  const int b = blockIdx.x;
  const int tid = threadIdx.x;
  const int w = tid >> 6, lane = tid & 63, lg = lane >> 4, lr = lane & 15;
  const float* xb = x + (size_t)b * (TT * EE);

  // stage x -> LDS frags: frag(mt,es) lane j = X[16mt+lr][32es+8lg+j]
#pragma unroll
  for (int i = 0; i < 6; ++i) {
    int idx = tid + 512 * i;
    int t = idx & 127, cb = idx >> 7;
    const float* p = xb + t * EE + cb * 8;
    float4 u = *(const float4*)p, v = *(const float4*)(p + 4);
    short8 h;
    h[0] = (short)f2bf(u.x); h[1] = (short)f2bf(u.y);
    h[2] = (short)f2bf(u.z); h[3] = (short)f2bf(u.w);
    h[4] = (short)f2bf(v.x); h[5] = (short)f2bf(v.y);
    h[6] = (short)f2bf(v.z); h[7] = (short)f2bf(v.w);
    *(short8*)(smem + ((t >> 4) * 6 + (cb >> 2)) * 1024 +
               ((cb & 3) * 16 + (t & 15)) * 16) = h;
  }
  __syncthreads();

  const short* wfq = wf;
  const short* wfk = wf + 36864;
  const short* wfv = wf + 73728;
  char* qbase = qws + (size_t)b * 49152 + lane * 16;
  char* kvb = kvws + (size_t)b * 98304;
  char* kbase = kvb + lane * 16;
  char* vgb = kvb + 49152;

  // unit tables: byte = (type<<4)|param; type 0=Qpair 1=Kpair 2=V
  const unsigned long long T0 = 0x1303120211011000ULL;
  const unsigned long long T1 = 0x2322211514200504ULL;
  const unsigned long long T2 = 0x2B2A292827262524ULL;
  const int u0 = (int)((0x130E0B0806040200ULL >> (w * 8)) & 0xFF);
  const int u1 = (int)((0x18130E0B08060402ULL >> (w * 8)) & 0xFF);

  for (int ui = u0; ui < u1; ++ui) {
    unsigned code = (unsigned)((ui < 8 ? T0 : (ui < 16 ? T1 : T2)) >> ((ui & 7) * 8)) & 0xFFu;
    int ty = code >> 4, p = code & 15;
    if (ty == 0)      proj_pair(smem, wfq, p, qbase + p * 1024, lg, lr, lane);
    else if (ty == 1) proj_pair(smem, wfk, p, kbase + p * 1024, lg, lr, lane);
    else              proj_v(smem, wfv, p, vgb, lg, lr, lane);
  }
}

// ---------------------------------------------------------------------------
// K2: attention with LDS-staged K/V (48KB region used twice -> 3 blocks/CU).
// Block = 1 batch, 8 waves, wave = q-tile. Staging is a pure linear copy
// (frag layout is already LDS-ready). 3 barriers. O overwrites d_out[b] only
// after B3 (all global V reads drained).
// ---------------------------------------------------------------------------
__global__ __launch_bounds__(512)
void attn_lds(const char* __restrict__ qws, char* __restrict__ kv) {
  __shared__ char smem[49152];
  const int b = blockIdx.x;
  const int tid = threadIdx.x;
  const int qt = tid >> 6, lane = tid & 63, lg = lane >> 4, lr = lane & 15;
  const char* kb = kv + (size_t)b * 98304;
  const char* vb = kb + 49152;
  const f32x4 zero = {0.f, 0.f, 0.f, 0.f};

  // ---- stage K -> LDS (each thread 6 x 16B, coalesced, frag-linear) ----
#pragma unroll
  for (int i = 0; i < 6; ++i) {
    int off = (qt * 6 + i) * 1024 + lane * 16;
    *(short8*)(smem + off) = *(const short8*)(kb + off);
  }

  // ---- Q B-frags: lane j -> Q[16qt+lr][32ha+8lg+j] ----
  short8 qb[6];
#pragma unroll
  for (int ha = 0; ha < 6; ++ha)
    qb[ha] = *(const short8*)(qws + ((size_t)(b * 48 + qt * 6 + ha) * 64 + lane) * 16);

  __syncthreads();  // B1: K in LDS

  // ---- QK^T from LDS: S^T = mfma(K-frag, qb) ----
  short8 pa[4];
  {
    f32x4 sa[8];
#pragma unroll
    for (int kt = 0; kt < 8; ++kt) sa[kt] = zero;
#pragma unroll
    for (int kt = 0; kt < 8; ++kt) {
      if (kt <= qt) {
#pragma unroll
        for (int ha = 0; ha < 6; ++ha) {
          short8 ka = *(const short8*)(smem + (kt * 6 + ha) * 1024 + lane * 16);
          sa[kt] = __builtin_amdgcn_mfma_f32_16x16x32_bf16(ka, qb[ha], sa[kt], 0, 0, 0);
        }
      }
    }

    // softmax over row q=16qt+lr (in-lane + 2 shfl_xor across lg)
    const float CSC = SCALE_F * LOG2E_F;
    float m = -INFINITY;
#pragma unroll
    for (int kt = 0; kt < 8; ++kt)
      if (kt <= qt) {
#pragma unroll
        for (int r = 0; r < 4; ++r) {
          float v = sa[kt][r] * CSC;
          if (kt == qt && 4 * lg + r > lr) v = -INFINITY;  // causal diagonal
          sa[kt][r] = v;
          m = fmaxf(m, v);
        }
      }
    m = fmaxf(m, __shfl_xor(m, 16));
    m = fmaxf(m, __shfl_xor(m, 32));
    float sum = 0.f;
#pragma unroll
    for (int kt = 0; kt < 8; ++kt)
      if (kt <= qt) {
#pragma unroll
        for (int r = 0; r < 4; ++r) {
          float p = exp2f(sa[kt][r] - m);
          sa[kt][r] = p;
          sum += p;
        }
      }
    sum += __shfl_xor(sum, 16);
    sum += __shfl_xor(sum, 32);
    const float rinv = 1.0f / sum;

    unsigned pw[8][2];
#pragma unroll
    for (int kt = 0; kt < 8; ++kt) { pw[kt][0] = 0u; pw[kt][1] = 0u; }
#pragma unroll
    for (int kt = 0; kt < 8; ++kt)
      if (kt <= qt) {
        pw[kt][0] = pack2bf(sa[kt][0] * rinv, sa[kt][1] * rinv);
        pw[kt][1] = pack2bf(sa[kt][2] * rinv, sa[kt][3] * rinv);
      }

    // pa[tp]: lane j -> P[q=16qt+lr][t=32tp+8lg+j]
#pragma unroll
    for (int tp = 0; tp < 4; ++tp) {
      union { unsigned d[4]; short8 v; } au;
#pragma unroll
      for (int i = 0; i < 4; ++i) {
        int sl = ((2 * (lg & 1) + (i >> 1)) << 4) | lr;
        unsigned lo = (unsigned)__shfl((int)pw[2 * tp][i & 1], sl);
        unsigned hi = (unsigned)__shfl((int)pw[2 * tp + 1][i & 1], sl);
        au.d[i] = (lg >> 1) ? hi : lo;
      }
      pa[tp] = au.v;
    }
  }
  __syncthreads();  // B2: all K LDS reads done; LDS reusable for V

  // ---- stage V -> LDS (same linear copy) ----
#pragma unroll
  for (int i = 0; i < 6; ++i) {
    int off = (qt * 6 + i) * 1024 + lane * 16;
    *(short8*)(smem + off) = *(const short8*)(vb + off);
  }
  __syncthreads();  // B3: V in LDS; all global K/V reads drained

  // ---- O^T = mfma(V^T-frag, pa): lane holds O^T[16ht+4lg+r][16qt+lr] ----
  f32x4 ot[12];
#pragma unroll
  for (int ht = 0; ht < 12; ++ht) ot[ht] = zero;
#pragma unroll
  for (int tp = 0; tp < 4; ++tp) {
    if (tp <= (qt >> 1)) {
#pragma unroll
      for (int ht = 0; ht < 12; ++ht) {
        short8 va = *(const short8*)(smem + (tp * 12 + ht) * 1024 + lane * 16);
        ot[ht] = __builtin_amdgcn_mfma_f32_16x16x32_bf16(va, pa[tp], ot[ht], 0, 0, 0);
      }
    }
  }

  // ---- O[q][h]: 4 consecutive h per lane -> f32x4 stores (overwrites kv[b]) ----
  float* ob = (float*)(kv + (size_t)b * 98304);
#pragma unroll
  for (int ht = 0; ht < 12; ++ht)
    *(f32x4*)(ob + (16 * qt + lr) * HH + 16 * ht + 4 * lg) = ot[ht];
}

extern "C" void kernel_launch(void* const* d_in, const int* in_sizes, int n_in,
                              void* d_out, int out_size, void* d_ws, size_t ws_size,
                              hipStream_t stream) {
  const float* x  = (const float*)d_in[0];
  const float* Wq = (const float*)d_in[1];
  const float* Wk = (const float*)d_in[2];
  const float* Wv = (const float*)d_in[3];
  int Bn = in_sizes[0] / (TT * EE);

  char*  qws = (char*)d_ws;                                 // Bn*49152 B
  short* wsW = (short*)((char*)d_ws + (size_t)Bn * 49152);  // 221184 B

  hipLaunchKernelGGL(pack_w, dim3(54), dim3(256), 0, stream, Wq, Wk, Wv, wsW);
  hipLaunchKernelGGL(qkv_gemm, dim3(Bn), dim3(512), 0, stream,
                     x, wsW, qws, (char*)d_out);
  hipLaunchKernelGGL(attn_lds, dim3(Bn), dim3(512), 0, stream,
                     qws, (char*)d_out);
}

// Round 11
// 242.647 us; speedup vs baseline: 2.2843x; 1.0319x over previous
//
#include <hip/hip_runtime.h>

// Problem constants
#define TT 128
#define EE 192
#define HH 192
#define SCALE_F 0.07216878364870322f
#define LOG2E_F 1.4426950408889634f

typedef float f32x4 __attribute__((ext_vector_type(4)));
typedef short short8 __attribute__((ext_vector_type(8)));
typedef short short4v __attribute__((ext_vector_type(4)));

__device__ inline unsigned short f2bf(float x) {
  union { float f; unsigned u; } v; v.f = x;
  unsigned r = v.u + 0x7FFFu + ((v.u >> 16) & 1u);
  return (unsigned short)(r >> 16);
}
__device__ inline unsigned pack2bf(float a, float b) {
  return (unsigned)f2bf(a) | ((unsigned)f2bf(b) << 16);
}

// ---------------------------------------------------------------------------
// pack_w: W[h][e] fp32 -> frag-major bf16 in ws.
// frag f = widx*72 + tile*6 + es; lane(lg,lr) j=0..7 -> W[16*tile+lr][32*es+8*lg+j]
// ---------------------------------------------------------------------------
__global__ void pack_w(const float* __restrict__ Wq, const float* __restrict__ Wk,
                       const float* __restrict__ Wv, short* __restrict__ out) {
  int f = blockIdx.x * 4 + (threadIdx.x >> 6);
  int lane = threadIdx.x & 63, lg = lane >> 4, lr = lane & 15;
  int widx = f / 72, rem = f % 72, tile = rem / 6, es = rem % 6;
  const float* W = (widx == 0) ? Wq : ((widx == 1) ? Wk : Wv);
  const float* p = W + (16 * tile + lr) * EE + 32 * es + 8 * lg;
  float4 a = *(const float4*)p;
  float4 b = *(const float4*)(p + 4);
  short8 h;
  h[0] = (short)f2bf(a.x); h[1] = (short)f2bf(a.y);
  h[2] = (short)f2bf(a.z); h[3] = (short)f2bf(a.w);
  h[4] = (short)f2bf(b.x); h[5] = (short)f2bf(b.y);
  h[6] = (short)f2bf(b.z); h[7] = (short)f2bf(b.w);
  *(short8*)(out + ((size_t)f * 64 + lane) * 8) = h;
}

// ---------------------------------------------------------------------------
// proj_pair: transpose-GEMM + shuffle for Q or K tile-pair p (h-cols 32p..+31).
// Weights (12 frags) register-resident; loops 4 local m-tiles from LDS.
// Produces frag lane j -> M[16mt+lr][32p+8lg+j]; dstbase pre-offset by
// p*1024 + mtoff*6144 + lane*16; per-local-mt stride 6144.
// ---------------------------------------------------------------------------
__device__ __forceinline__ void proj_pair(const char* smem, const short* wsrc,
                                          int p, char* dstbase,
                                          int lg, int lr, int lane) {
  const f32x4 zero = {0.f, 0.f, 0.f, 0.f};
  short8 wg[12];
#pragma unroll
  for (int i = 0; i < 12; ++i)
    wg[i] = *(const short8*)((const char*)wsrc + ((size_t)(p * 12 + i) * 64 + lane) * 16);
#pragma unroll
  for (int mt = 0; mt < 4; ++mt) {
    f32x4 a0 = zero, a1 = zero;
#pragma unroll
    for (int es = 0; es < 6; ++es) {
      short8 xf = *(const short8*)(smem + (mt * 6 + es) * 1024 + lane * 16);
      a0 = __builtin_amdgcn_mfma_f32_16x16x32_bf16(wg[es], xf, a0, 0, 0, 0);
      a1 = __builtin_amdgcn_mfma_f32_16x16x32_bf16(wg[6 + es], xf, a1, 0, 0, 0);
    }
    unsigned w00 = pack2bf(a0[0], a0[1]), w01 = pack2bf(a0[2], a0[3]);
    unsigned w10 = pack2bf(a1[0], a1[1]), w11 = pack2bf(a1[2], a1[3]);
    union { unsigned d[4]; short8 v; } au;
#pragma unroll
    for (int i = 0; i < 4; ++i) {
      int sl = ((2 * (lg & 1) + (i >> 1)) << 4) | lr;
      unsigned v0 = (unsigned)__shfl((int)(i & 1 ? w01 : w00), sl);
      unsigned v1 = (unsigned)__shfl((int)(i & 1 ? w11 : w10), sl);
      au.d[i] = (lg >> 1) ? v1 : v0;
    }
    *(short8*)(dstbase + mt * 6144) = au.v;
  }
}

// ---------------------------------------------------------------------------
// proj_v: row-major GEMM for V n-tile nt; direct V^T A-frag stores (8B contig).
// Loops 4 local m-tiles; global m-tile = mtoff + mt.
// ---------------------------------------------------------------------------
__device__ __forceinline__ void proj_v(const char* smem, const short* wfv,
                                       int nt, char* vgb, int mtoff,
                                       int lg, int lr, int lane) {
  const f32x4 zero = {0.f, 0.f, 0.f, 0.f};
  short8 wg[6];
#pragma unroll
  for (int i = 0; i < 6; ++i)
    wg[i] = *(const short8*)((const char*)wfv + ((size_t)(nt * 6 + i) * 64 + lane) * 16);
#pragma unroll
  for (int mt = 0; mt < 4; ++mt) {
    f32x4 a0 = zero;
#pragma unroll
    for (int es = 0; es < 6; ++es) {
      short8 xf = *(const short8*)(smem + (mt * 6 + es) * 1024 + lane * 16);
      a0 = __builtin_amdgcn_mfma_f32_16x16x32_bf16(xf, wg[es], a0, 0, 0, 0);
    }
    int mtg = mtoff + mt;
    short4v p4;
    p4[0] = (short)f2bf(a0[0]); p4[1] = (short)f2bf(a0[1]);
    p4[2] = (short)f2bf(a0[2]); p4[3] = (short)f2bf(a0[3]);
    *(short4v*)(vgb + (size_t)((mtg >> 1) * 12 + nt) * 1024 +
                ((2 * (mtg & 1) + (lg >> 1)) * 16 + lr) * 16 + (lg & 1) * 8) = p4;
  }
}

// ---------------------------------------------------------------------------
// K1: QKV projection GEMM. Block = (batch, half): 64 x-rows, 24KB LDS,
// 8 waves, ONE barrier -> 6 blocks/CU ceiling. 24 units over 8 waves:
// waves 0-3 {pair,pair,V}, waves 4-7 {pair,V,V} (pair p<6 = Q, else K).
// ---------------------------------------------------------------------------
__global__ __launch_bounds__(512)
void qkv_gemm(const float* __restrict__ x, const short* __restrict__ wf,
              char* __restrict__ qws, char* __restrict__ kvws) {
  __shared__ char smem[24576];
  const int bh = blockIdx.x, b = bh >> 1, half = bh & 1;
  const int tid = threadIdx.x;
  const int w = tid >> 6, lane = tid & 63, lg = lane >> 4, lr = lane & 15;
  const float* xb = x + (size_t)b * (TT * EE) + (size_t)half * 64 * EE;

  // stage 64 rows -> 24 LDS frags: frag(mt,es) lane j = X[16mt+lr][32es+8lg+j]
#pragma unroll
  for (int i = 0; i < 3; ++i) {
    int idx = tid + 512 * i;          // 1536 (row, col-block) pairs
    int t = idx & 63, cb = idx >> 6;  // row 0..63, 8-col block 0..23
    const float* p = xb + t * EE + cb * 8;
    float4 u = *(const float4*)p, v = *(const float4*)(p + 4);
    short8 h;
    h[0] = (short)f2bf(u.x); h[1] = (short)f2bf(u.y);
    h[2] = (short)f2bf(u.z); h[3] = (short)f2bf(u.w);
    h[4] = (short)f2bf(v.x); h[5] = (short)f2bf(v.y);
    h[6] = (short)f2bf(v.z); h[7] = (short)f2bf(v.w);
    *(short8*)(smem + ((t >> 4) * 6 + (cb >> 2)) * 1024 +
               ((cb & 3) * 16 + (t & 15)) * 16) = h;
  }
  __syncthreads();

  const short* wfq = wf;
  const short* wfk = wf + 36864;
  const short* wfv = wf + 73728;
  const int mtoff = half * 4;
  char* kvb = kvws + (size_t)b * 98304;
  char* qbase = qws + (size_t)b * 49152 + mtoff * 6144 + lane * 16;
  char* kbase = kvb + mtoff * 6144 + lane * 16;
  char* vgb = kvb + 49152;

  // unit table: byte = (type<<4)|param; type 0 = pair (param<6 Q else K-6),
  // type 1 = V. Wave w executes entries 3w..3w+2.
  const unsigned long long T0 = 0x0504110302100100ULL;  // entries 0..7
  const unsigned long long T1 = 0x0915140813070612ULL;  // entries 8..15
  const unsigned long long T2 = 0x1B1A0B19180A1716ULL;  // entries 16..23

#pragma unroll
  for (int i = 0; i < 3; ++i) {
    int ui = w * 3 + i;
    unsigned code = (unsigned)((ui < 8 ? T0 : (ui < 16 ? T1 : T2)) >> ((ui & 7) * 8)) & 0xFFu;
    int ty = code >> 4, p = code & 15;
    if (ty == 0) {
      if (p < 6) proj_pair(smem, wfq, p, qbase + p * 1024, lg, lr, lane);
      else       proj_pair(smem, wfk, p - 6, kbase + (p - 6) * 1024, lg, lr, lane);
    } else {
      proj_v(smem, wfv, p, vgb, mtoff, lg, lr, lane);
    }
  }
}

// ---------------------------------------------------------------------------
// K2: attention with LDS-staged K/V (48KB region used twice). Block = 1 batch,
// 8 waves, wave = q-tile. 3 barriers. O overwrites d_out[b] after B3.
// ---------------------------------------------------------------------------
__global__ __launch_bounds__(512)
void attn_lds(const char* __restrict__ qws, char* __restrict__ kv) {
  __shared__ char smem[49152];
  const int b = blockIdx.x;
  const int tid = threadIdx.x;
  const int qt = tid >> 6, lane = tid & 63, lg = lane >> 4, lr = lane & 15;
  const char* kb = kv + (size_t)b * 98304;
  const char* vb = kb + 49152;
  const f32x4 zero = {0.f, 0.f, 0.f, 0.f};

  // ---- stage K -> LDS (each thread 6 x 16B, coalesced, frag-linear) ----
#pragma unroll
  for (int i = 0; i < 6; ++i) {
    int off = (qt * 6 + i) * 1024 + lane * 16;
    *(short8*)(smem + off) = *(const short8*)(kb + off);
  }

  // ---- Q B-frags: lane j -> Q[16qt+lr][32ha+8lg+j] ----
  short8 qb[6];
#pragma unroll
  for (int ha = 0; ha < 6; ++ha)
    qb[ha] = *(const short8*)(qws + ((size_t)(b * 48 + qt * 6 + ha) * 64 + lane) * 16);

  __syncthreads();  // B1: K in LDS

  // ---- QK^T from LDS: S^T = mfma(K-frag, qb) ----
  short8 pa[4];
  {
    f32x4 sa[8];
#pragma unroll
    for (int kt = 0; kt < 8; ++kt) sa[kt] = zero;
#pragma unroll
    for (int kt = 0; kt < 8; ++kt) {
      if (kt <= qt) {
#pragma unroll
        for (int ha = 0; ha < 6; ++ha) {
          short8 ka = *(const short8*)(smem + (kt * 6 + ha) * 1024 + lane * 16);
          sa[kt] = __builtin_amdgcn_mfma_f32_16x16x32_bf16(ka, qb[ha], sa[kt], 0, 0, 0);
        }
      }
    }

    // softmax over row q=16qt+lr (in-lane + 2 shfl_xor across lg)
    const float CSC = SCALE_F * LOG2E_F;
    float m = -INFINITY;
#pragma unroll
    for (int kt = 0; kt < 8; ++kt)
      if (kt <= qt) {
#pragma unroll
        for (int r = 0; r < 4; ++r) {
          float v = sa[kt][r] * CSC;
          if (kt == qt && 4 * lg + r > lr) v = -INFINITY;  // causal diagonal
          sa[kt][r] = v;
          m = fmaxf(m, v);
        }
      }
    m = fmaxf(m, __shfl_xor(m, 16));
    m = fmaxf(m, __shfl_xor(m, 32));
    float sum = 0.f;
#pragma unroll
    for (int kt = 0; kt < 8; ++kt)
      if (kt <= qt) {
#pragma unroll
        for (int r = 0; r < 4; ++r) {
          float p = exp2f(sa[kt][r] - m);
          sa[kt][r] = p;
          sum += p;
        }
      }
    sum += __shfl_xor(sum, 16);
    sum += __shfl_xor(sum, 32);
    const float rinv = 1.0f / sum;

    unsigned pw[8][2];
#pragma unroll
    for (int kt = 0; kt < 8; ++kt) { pw[kt][0] = 0u; pw[kt][1] = 0u; }
#pragma unroll
    for (int kt = 0; kt < 8; ++kt)
      if (kt <= qt) {
        pw[kt][0] = pack2bf(sa[kt][0] * rinv, sa[kt][1] * rinv);
        pw[kt][1] = pack2bf(sa[kt][2] * rinv, sa[kt][3] * rinv);
      }

    // pa[tp]: lane j -> P[q=16qt+lr][t=32tp+8lg+j]
#pragma unroll
    for (int tp = 0; tp < 4; ++tp) {
      union { unsigned d[4]; short8 v; } au;
#pragma unroll
      for (int i = 0; i < 4; ++i) {
        int sl = ((2 * (lg & 1) + (i >> 1)) << 4) | lr;
        unsigned lo = (unsigned)__shfl((int)pw[2 * tp][i & 1], sl);
        unsigned hi = (unsigned)__shfl((int)pw[2 * tp + 1][i & 1], sl);
        au.d[i] = (lg >> 1) ? hi : lo;
      }
      pa[tp] = au.v;
    }
  }
  __syncthreads();  // B2: all K LDS reads done; LDS reusable for V

  // ---- stage V -> LDS (same linear copy) ----
#pragma unroll
  for (int i = 0; i < 6; ++i) {
    int off = (qt * 6 + i) * 1024 + lane * 16;
    *(short8*)(smem + off) = *(const short8*)(vb + off);
  }
  __syncthreads();  // B3: V in LDS; all global K/V reads drained

  // ---- O^T = mfma(V^T-frag, pa): lane holds O^T[16ht+4lg+r][16qt+lr] ----
  f32x4 ot[12];
#pragma unroll
  for (int ht = 0; ht < 12; ++ht) ot[ht] = zero;
#pragma unroll
  for (int tp = 0; tp < 4; ++tp) {
    if (tp <= (qt >> 1)) {
#pragma unroll
      for (int ht = 0; ht < 12; ++ht) {
        short8 va = *(const short8*)(smem + (tp * 12 + ht) * 1024 + lane * 16);
        ot[ht] = __builtin_amdgcn_mfma_f32_16x16x32_bf16(va, pa[tp], ot[ht], 0, 0, 0);
      }
    }
  }

  // ---- O[q][h]: 4 consecutive h per lane -> f32x4 stores (overwrites kv[b]) ----
  float* ob = (float*)(kv + (size_t)b * 98304);
#pragma unroll
  for (int ht = 0; ht < 12; ++ht)
    *(f32x4*)(ob + (16 * qt + lr) * HH + 16 * ht + 4 * lg) = ot[ht];
}

extern "C" void kernel_launch(void* const* d_in, const int* in_sizes, int n_in,
                              void* d_out, int out_size, void* d_ws, size_t ws_size,
                              hipStream_t stream) {
  const float* x  = (const float*)d_in[0];
  const float* Wq = (const float*)d_in[1];
  const float* Wk = (const float*)d_in[2];
  const float* Wv = (const float*)d_in[3];
  int Bn = in_sizes[0] / (TT * EE);

  char*  qws = (char*)d_ws;                                 // Bn*49152 B
  short* wsW = (short*)((char*)d_ws + (size_t)Bn * 49152);  // 221184 B

  hipLaunchKernelGGL(pack_w, dim3(54), dim3(256), 0, stream, Wq, Wk, Wv, wsW);
  hipLaunchKernelGGL(qkv_gemm, dim3(2 * Bn), dim3(512), 0, stream,
                     x, wsW, qws, (char*)d_out);
  hipLaunchKernelGGL(attn_lds, dim3(Bn), dim3(512), 0, stream,
                     qws, (char*)d_out);
}